// Round 1
// baseline (109.925 us; speedup 1.0000x reference)
//
#include <hip/hip_runtime.h>

#define NROWS 16384
#define DDIM  256

// ---------------------------------------------------------------------------
// k1: one pass over X computing v = X^T (X b).
// Wave-per-row: lane l holds columns 4l..4l+3 (float4). For each row:
//   t = x_frag . b_frag ; butterfly-reduce over 64 lanes -> u_r (all lanes)
//   vacc += u_r * x_frag   (register accumulation, 16 rows per wave)
// Block combines 4 wave partials in LDS, writes per-block partial v to ws.
// 256 blocks x 64 rows = 16384 rows. Deterministic (no atomics).
// ---------------------------------------------------------------------------
__global__ __launch_bounds__(256) void k1_partial_v(const float* __restrict__ X,
                                                    const float* __restrict__ b,
                                                    float* __restrict__ partials) {
    const int tid  = threadIdx.x;
    const int lane = tid & 63;
    const int wave = tid >> 6;
    const int bid  = blockIdx.x;

    const float4* X4 = (const float4*)X;
    const float4  bf = ((const float4*)b)[lane];

    float4 vacc = make_float4(0.f, 0.f, 0.f, 0.f);
    const int row0 = bid * 64 + wave * 16;
    #pragma unroll
    for (int i = 0; i < 16; ++i) {
        const int r = row0 + i;
        const float4 x = X4[r * 64 + lane];
        float t = x.x * bf.x + x.y * bf.y + x.z * bf.z + x.w * bf.w;
        #pragma unroll
        for (int off = 32; off; off >>= 1) t += __shfl_xor(t, off, 64);
        vacc.x += t * x.x;
        vacc.y += t * x.y;
        vacc.z += t * x.z;
        vacc.w += t * x.w;
    }

    __shared__ float sp[4][DDIM];
    ((float4*)sp[wave])[lane] = vacc;
    __syncthreads();
    const float s = sp[0][tid] + sp[1][tid] + sp[2][tid] + sp[3][tid];
    partials[bid * DDIM + tid] = s;   // coalesced
}

// ---------------------------------------------------------------------------
// k2 (single block): v[t] = sum_b partials[b][t]; then w2 = W v.
// Wave-per-row of W: 4 waves x 64 rows. Coalesced 1KB row loads.
// ---------------------------------------------------------------------------
__global__ __launch_bounds__(256) void k2_w2(const float* __restrict__ partials,
                                             const float* __restrict__ W,
                                             float* __restrict__ w2) {
    const int tid = threadIdx.x;
    __shared__ __align__(16) float sv[DDIM];

    float s = 0.f;
    for (int bb = 0; bb < 256; ++bb) s += partials[bb * DDIM + tid];  // coalesced
    sv[tid] = s;
    __syncthreads();

    const int lane = tid & 63;
    const int wave = tid >> 6;
    const float4 vf = ((const float4*)sv)[lane];
    const float4* W4 = (const float4*)W;

    for (int i = 0; i < 64; ++i) {
        const int k = wave * 64 + i;
        const float4 w = W4[k * 64 + lane];
        float t = w.x * vf.x + w.y * vf.y + w.z * vf.z + w.w * vf.w;
        #pragma unroll
        for (int off = 32; off; off >>= 1) t += __shfl_xor(t, off, 64);
        if (lane == 0) w2[k] = t;
    }
}

// ---------------------------------------------------------------------------
// k3: g = X w2. Second pass over X, same wave-per-row dot structure as k1.
// ---------------------------------------------------------------------------
__global__ __launch_bounds__(256) void k3_g(const float* __restrict__ X,
                                            const float* __restrict__ w2,
                                            float* __restrict__ g) {
    const int tid  = threadIdx.x;
    const int lane = tid & 63;
    const int wave = tid >> 6;
    const int bid  = blockIdx.x;

    const float4* X4 = (const float4*)X;
    const float4  wf = ((const float4*)w2)[lane];

    const int row0 = bid * 64 + wave * 16;
    #pragma unroll
    for (int i = 0; i < 16; ++i) {
        const int r = row0 + i;
        const float4 x = X4[r * 64 + lane];
        float t = x.x * wf.x + x.y * wf.y + x.z * wf.z + x.w * wf.w;
        #pragma unroll
        for (int off = 32; off; off >>= 1) t += __shfl_xor(t, off, 64);
        if (lane == 0) g[r] = t;
    }
}

extern "C" void kernel_launch(void* const* d_in, const int* in_sizes, int n_in,
                              void* d_out, int out_size, void* d_ws, size_t ws_size,
                              hipStream_t stream) {
    const float* X = (const float*)d_in[0];   // (16384, 256)
    const float* W = (const float*)d_in[1];   // (256, 256)
    const float* b = (const float*)d_in[2];   // (256,)
    float* out = (float*)d_out;               // (16384,)

    float* partials = (float*)d_ws;           // 256 blocks x 256 floats = 256 KB
    float* w2       = partials + 256 * DDIM;  // 256 floats

    k1_partial_v<<<256, 256, 0, stream>>>(X, b, partials);
    k2_w2<<<1, 256, 0, stream>>>(partials, W, w2);
    k3_g<<<256, 256, 0, stream>>>(X, w2, out);
}

// Round 2
// 86.910 us; speedup vs baseline: 1.2648x; 1.2648x over previous
//
#include <hip/hip_runtime.h>

#define NROWS 16384
#define DDIM  256

// ---------------------------------------------------------------------------
// k1: one pass over X computing v = X^T (X b), accumulated via atomics.
// Wave-per-row: lane l holds columns 4l..4l+3 (float4). Per row:
//   t = x . b ; 6-step butterfly -> u_r on all lanes ; vacc += u_r * x
// 8 rows per wave (independent chains -> ILP). Block combines 4 wave
// partials in LDS, then one atomicAdd per thread into global v[256].
// Grid 512 x 256 threads = 2 blocks/CU -> 8 waves/CU.
// ---------------------------------------------------------------------------
__global__ __launch_bounds__(256) void k1_v(const float* __restrict__ X,
                                            const float* __restrict__ b,
                                            float* __restrict__ v) {
    const int tid  = threadIdx.x;
    const int lane = tid & 63;
    const int wave = tid >> 6;
    const int bid  = blockIdx.x;

    const float4* X4 = (const float4*)X;
    const float4  bf = ((const float4*)b)[lane];

    float4 vacc = make_float4(0.f, 0.f, 0.f, 0.f);
    const int row0 = bid * 32 + wave * 8;
    #pragma unroll
    for (int i = 0; i < 8; ++i) {
        const int r = row0 + i;
        const float4 x = X4[r * 64 + lane];
        float t = x.x * bf.x + x.y * bf.y + x.z * bf.z + x.w * bf.w;
        #pragma unroll
        for (int off = 32; off; off >>= 1) t += __shfl_xor(t, off, 64);
        vacc.x += t * x.x;
        vacc.y += t * x.y;
        vacc.z += t * x.z;
        vacc.w += t * x.w;
    }

    __shared__ float sp[4][DDIM];
    ((float4*)sp[wave])[lane] = vacc;
    __syncthreads();
    const float s = sp[0][tid] + sp[1][tid] + sp[2][tid] + sp[3][tid];
    atomicAdd(&v[tid], s);  // device-scope, 512 adds/address, coalesced per wave
}

// ---------------------------------------------------------------------------
// k2: w2 = W v, 64 blocks x 4 waves, wave-per-row of W (256 rows).
// Each wave: lane loads 16B of the W row + 16B of v, dot, butterfly, store.
// ---------------------------------------------------------------------------
__global__ __launch_bounds__(256) void k2_w2(const float* __restrict__ W,
                                             const float* __restrict__ v,
                                             float* __restrict__ w2) {
    const int tid  = threadIdx.x;
    const int lane = tid & 63;
    const int wave = tid >> 6;
    const int row  = blockIdx.x * 4 + wave;

    const float4 vf = ((const float4*)v)[lane];
    const float4 w  = ((const float4*)W)[row * 64 + lane];
    float t = w.x * vf.x + w.y * vf.y + w.z * vf.z + w.w * vf.w;
    #pragma unroll
    for (int off = 32; off; off >>= 1) t += __shfl_xor(t, off, 64);
    if (lane == 0) w2[row] = t;
}

// ---------------------------------------------------------------------------
// k3: g = X w2. Second pass over X, same structure as k1 (8 rows/wave).
// ---------------------------------------------------------------------------
__global__ __launch_bounds__(256) void k3_g(const float* __restrict__ X,
                                            const float* __restrict__ w2,
                                            float* __restrict__ g) {
    const int tid  = threadIdx.x;
    const int lane = tid & 63;
    const int wave = tid >> 6;
    const int bid  = blockIdx.x;

    const float4* X4 = (const float4*)X;
    const float4  wf = ((const float4*)w2)[lane];

    const int row0 = bid * 32 + wave * 8;
    #pragma unroll
    for (int i = 0; i < 8; ++i) {
        const int r = row0 + i;
        const float4 x = X4[r * 64 + lane];
        float t = x.x * wf.x + x.y * wf.y + x.z * wf.z + x.w * wf.w;
        #pragma unroll
        for (int off = 32; off; off >>= 1) t += __shfl_xor(t, off, 64);
        if (lane == 0) g[r] = t;
    }
}

extern "C" void kernel_launch(void* const* d_in, const int* in_sizes, int n_in,
                              void* d_out, int out_size, void* d_ws, size_t ws_size,
                              hipStream_t stream) {
    const float* X = (const float*)d_in[0];   // (16384, 256)
    const float* W = (const float*)d_in[1];   // (256, 256)
    const float* b = (const float*)d_in[2];   // (256,)
    float* out = (float*)d_out;               // (16384,)

    float* v  = (float*)d_ws;                 // 256 floats (atomic accumulator)
    float* w2 = v + DDIM;                     // 256 floats

    hipMemsetAsync(v, 0, DDIM * sizeof(float), stream);  // graph-capturable
    k1_v <<<512, 256, 0, stream>>>(X, b, v);
    k2_w2<<< 64, 256, 0, stream>>>(W, v, w2);
    k3_g <<<512, 256, 0, stream>>>(X, w2, out);
}